// Round 2
// baseline (481.275 us; speedup 1.0000x reference)
//
#include <hip/hip_runtime.h>
#include <hip/hip_bf16.h>

// Problem constants (match reference): K=4, B=4096, T=32, D=128
constexpr int K = 4;
constexpr int B = 4096;   // power of two: kb>>12 = k, kb&4095 = b
constexpr int T = 32;
constexpr int D = 128;
constexpr int TT = T * T;   // 1024 pairs per anchor
constexpr int TD = T * D;   // 4096 floats per anchor's nbr_embed

// true clang vector type -> legal operand for __builtin_nontemporal_store
typedef float f4 __attribute__((ext_vector_type(4)));

__device__ __forceinline__ float dot4(f4 a, f4 b) {
    return a.x * b.x + a.y * b.y + a.z * b.z + a.w * b.w;
}

// butterfly sum across the 32 lanes of a half-wave (xor masks <=16 stay
// within each 32-lane half of the wave-64)
__device__ __forceinline__ float hreduce32(float p) {
    #pragma unroll
    for (int m = 16; m >= 1; m >>= 1) p += __shfl_xor(p, m, 64);
    return p;
}

// ---------------------------------------------------------------------------
// Kernel 1: gather neighbor rows -> nbr (256 MB NT stream), compute nsim[t]
// and the 32-bit same-label mask; stash both into the first 33 dwords of
// this anchor's maskf region (overwritten with real mask values by kernel 2).
// ---------------------------------------------------------------------------
__global__ __launch_bounds__(256) void k_gather_nsim(
    const float* __restrict__ semb,     // [K,B,D]
    const int*   __restrict__ slabels,  // [K,B]
    const int*   __restrict__ topk,     // [K,B,T]
    float* __restrict__ nbr,            // [K,B,T,D]
    float* __restrict__ stash)          // == maskf base [K,B,T,T]
{
    const int kb  = blockIdx.x;
    const int k   = kb >> 12;
    const int tid = threadIdx.x;

    __shared__ f4    anchor4[T];   // anchor row, 32 x float4
    __shared__ int   idx_s[T];
    __shared__ float nsim_s[T];

    const int my_label = slabels[kb];
    int same = 0;
    if (tid < T) {
        const int idx = topk[kb * T + tid];
        idx_s[tid] = idx;
        same = (slabels[(k << 12) + idx] == my_label) ? 1 : 0;
        anchor4[tid] =
            reinterpret_cast<const f4*>(semb + (size_t)kb * D)[tid];
    }
    // wave-wide ballot; wave 0's low 32 bits are the same-label mask
    const unsigned long long bal = __ballot(same);
    __syncthreads();

    const f4* semb4 = reinterpret_cast<const f4*>(semb + (size_t)k * B * D);
    f4*       nbr4  = reinterpret_cast<f4*>(nbr + (size_t)kb * TD);

    // chunk c = tid + 256j -> row t = 8j + (tid>>5), d4 = tid&31 (invariant)
    const int w  = tid >> 5;
    const int d4 = tid & 31;
    const f4  a  = anchor4[d4];
    const int i0 = idx_s[w], i1 = idx_s[8 + w], i2 = idx_s[16 + w], i3 = idx_s[24 + w];

    // 4 independent gather loads (MLP), then 4 streaming stores, then reduces
    const f4 s0 = semb4[(size_t)i0 * (D / 4) + d4];
    const f4 s1 = semb4[(size_t)i1 * (D / 4) + d4];
    const f4 s2 = semb4[(size_t)i2 * (D / 4) + d4];
    const f4 s3 = semb4[(size_t)i3 * (D / 4) + d4];
    __builtin_nontemporal_store(s0, nbr4 + ((0  + w) * (D / 4) + d4));
    __builtin_nontemporal_store(s1, nbr4 + ((8  + w) * (D / 4) + d4));
    __builtin_nontemporal_store(s2, nbr4 + ((16 + w) * (D / 4) + d4));
    __builtin_nontemporal_store(s3, nbr4 + ((24 + w) * (D / 4) + d4));

    const float p0 = hreduce32(dot4(a, s0));
    const float p1 = hreduce32(dot4(a, s1));
    const float p2 = hreduce32(dot4(a, s2));
    const float p3 = hreduce32(dot4(a, s3));
    if (d4 == 0) {
        nsim_s[0  + w] = p0;
        nsim_s[8  + w] = p1;
        nsim_s[16 + w] = p2;
        nsim_s[24 + w] = p3;
    }
    __syncthreads();

    float* st = stash + (size_t)kb * TT;
    if (tid < T) st[tid] = nsim_s[tid];                       // plain (L2-resident)
    if (tid == 32)                                            // wave 0 lane 32 has bal
        reinterpret_cast<unsigned*>(st)[T] = (unsigned)bal;
}

// ---------------------------------------------------------------------------
// Kernel 2: pure streaming pair-writer. Reads 33 dwords per anchor from the
// stash (start of its own maskf region), overwrites with pos/neg/mask.
// No LDS, no reductions — fill-grade store loop.
// ---------------------------------------------------------------------------
__global__ __launch_bounds__(256) void k_pairs(
    float* pos,     // [K,B,T,T]
    float* neg,     // [K,B,T,T]
    float* maskf)   // [K,B,T,T]; first 33 dwords/anchor hold the stash
{
    const int kb  = blockIdx.x;
    const int tid = threadIdx.x;

    float* st = maskf + (size_t)kb * TT;
    const unsigned bits = reinterpret_cast<const unsigned*>(st)[T]; // uniform
    const int s_row = tid >> 3;        // (4*tid)>>5
    const int dq    = tid & 7;         // float4 index within d-row
    const float ps  = st[s_row];
    const f4    nd  = reinterpret_cast<const f4*>(st)[dq];
    __syncthreads();   // all stash reads complete before region overwrite

    const int ss       = (bits >> s_row) & 1;
    const unsigned ndb = ~(bits >> (dq * 4));   // inverted diff-side bits
    const int m0 = ss & (ndb & 1);
    const int m1 = ss & ((ndb >> 1) & 1);
    const int m2 = ss & ((ndb >> 2) & 1);
    const int m3 = ss & ((ndb >> 3) & 1);

    f4 pv, nv, mv;
    pv.x = m0 ? ps : 0.0f;  nv.x = m0 ? nd.x : 0.0f;  mv.x = (float)m0;
    pv.y = m1 ? ps : 0.0f;  nv.y = m1 ? nd.y : 0.0f;  mv.y = (float)m1;
    pv.z = m2 ? ps : 0.0f;  nv.z = m2 ? nd.z : 0.0f;  mv.z = (float)m2;
    pv.w = m3 ? ps : 0.0f;  nv.w = m3 ? nd.w : 0.0f;  mv.w = (float)m3;

    f4* pos4  = reinterpret_cast<f4*>(pos + (size_t)kb * TT);
    f4* neg4  = reinterpret_cast<f4*>(neg + (size_t)kb * TT);
    f4* mask4 = reinterpret_cast<f4*>(st);
    __builtin_nontemporal_store(pv, pos4  + tid);
    __builtin_nontemporal_store(nv, neg4  + tid);
    __builtin_nontemporal_store(mv, mask4 + tid);
}

extern "C" void kernel_launch(void* const* d_in, const int* in_sizes, int n_in,
                              void* d_out, int out_size, void* d_ws, size_t ws_size,
                              hipStream_t stream) {
    const float* semb    = (const float*)d_in[0];
    const int*   slabels = (const int*)d_in[1];
    const int*   topk    = (const int*)d_in[2];

    float* out = (float*)d_out;
    const size_t KBTT = (size_t)K * B * T * T;   // 16,777,216
    float* pos   = out;
    float* neg   = out + KBTT;
    float* maskf = out + 2 * KBTT;
    float* nbr   = out + 3 * KBTT;

    k_gather_nsim<<<dim3(K * B), dim3(256), 0, stream>>>(
        semb, slabels, topk, nbr, maskf);
    k_pairs<<<dim3(K * B), dim3(256), 0, stream>>>(pos, neg, maskf);
}

// Round 3
// 460.360 us; speedup vs baseline: 1.0454x; 1.0454x over previous
//
#include <hip/hip_runtime.h>
#include <hip/hip_bf16.h>

// Problem constants (match reference): K=4, B=4096, T=32, D=128
constexpr int K = 4;
constexpr int B = 4096;   // power of two: kb>>12 = k, kb&4095 = b
constexpr int T = 32;
constexpr int D = 128;
constexpr int TT = T * T;   // 1024 pairs per anchor
constexpr int TD = T * D;   // 4096 floats per anchor's nbr_embed

typedef float f4 __attribute__((ext_vector_type(4)));

__device__ __forceinline__ float dot4(f4 a, f4 b) {
    return a.x * b.x + a.y * b.y + a.z * b.z + a.w * b.w;
}

// butterfly sum across the 32 lanes of a half-wave (xor masks <=16 stay
// within each 32-lane half of the wave-64)
__device__ __forceinline__ float hreduce32(float p) {
    #pragma unroll
    for (int m = 16; m >= 1; m >>= 1) p += __shfl_xor(p, m, 64);
    return p;
}

// Fused: one 256-thread block per (k,b) anchor. PLAIN stores everywhere —
// the 6.3 TB/s fillBuffer yardstick uses plain stores; NT stores measured
// ~2.2x slower in R1/R2 (bypassing L2 loses write aggregation).
__global__ __launch_bounds__(256) void distance_layer_kernel(
    const float* __restrict__ semb,     // [K,B,D]
    const int*   __restrict__ slabels,  // [K,B]
    const int*   __restrict__ topk,     // [K,B,T]
    float* __restrict__ pos,            // [K,B,T,T]
    float* __restrict__ neg,            // [K,B,T,T]
    float* __restrict__ maskf,          // [K,B,T,T] (bool as 0.0/1.0)
    float* __restrict__ nbr)            // [K,B,T,D]
{
    const int kb  = blockIdx.x;
    const int k   = kb >> 12;
    const int tid = threadIdx.x;

    __shared__ f4    anchor4[T];   // anchor row, 32 x float4
    __shared__ int   idx_s[T];
    __shared__ float nsim_s[T];
    __shared__ int   same_s[T];

    // ---- Phase 0: stage indices, labels, anchor row -------------------
    const int my_label = slabels[kb];
    if (tid < T) {
        const int idx = topk[kb * T + tid];
        idx_s[tid]  = idx;
        same_s[tid] = (slabels[(k << 12) + idx] == my_label) ? 1 : 0;
        anchor4[tid] =
            reinterpret_cast<const f4*>(semb + (size_t)kb * D)[tid];
    }
    __syncthreads();

    // ---- Phase A: gather nbr rows + nsim dot products -----------------
    // chunk c = tid + 256j -> row t = 8j + (tid>>5), d4 = tid&31 (invariant)
    const f4* semb4 = reinterpret_cast<const f4*>(semb + (size_t)k * B * D);
    f4*       nbr4  = reinterpret_cast<f4*>(nbr + (size_t)kb * TD);

    const int w  = tid >> 5;
    const int d4 = tid & 31;
    const f4  a  = anchor4[d4];
    const int i0 = idx_s[w], i1 = idx_s[8 + w], i2 = idx_s[16 + w], i3 = idx_s[24 + w];

    // 4 independent gather loads (MLP), then 4 contiguous 1KB/wave stores
    const f4 s0 = semb4[(size_t)i0 * (D / 4) + d4];
    const f4 s1 = semb4[(size_t)i1 * (D / 4) + d4];
    const f4 s2 = semb4[(size_t)i2 * (D / 4) + d4];
    const f4 s3 = semb4[(size_t)i3 * (D / 4) + d4];
    nbr4[(0  + w) * (D / 4) + d4] = s0;
    nbr4[(8  + w) * (D / 4) + d4] = s1;
    nbr4[(16 + w) * (D / 4) + d4] = s2;
    nbr4[(24 + w) * (D / 4) + d4] = s3;

    const float p0 = hreduce32(dot4(a, s0));
    const float p1 = hreduce32(dot4(a, s1));
    const float p2 = hreduce32(dot4(a, s2));
    const float p3 = hreduce32(dot4(a, s3));
    if (d4 == 0) {
        nsim_s[0  + w] = p0;
        nsim_s[8  + w] = p1;
        nsim_s[16 + w] = p2;
        nsim_s[24 + w] = p3;
    }
    __syncthreads();

    // ---- Phase B: 1024 (s,d) pairs, 4 per thread as one float4 --------
    f4* pos4  = reinterpret_cast<f4*>(pos   + (size_t)kb * TT);
    f4* neg4  = reinterpret_cast<f4*>(neg   + (size_t)kb * TT);
    f4* mask4 = reinterpret_cast<f4*>(maskf + (size_t)kb * TT);

    const int s_row = tid >> 3;        // (4*tid)>>5
    const int d0    = (tid & 7) * 4;   // (4*tid)&31
    const int   ss = same_s[s_row];
    const float ps = nsim_s[s_row];

    f4 pv, nv, mv;
    {
        const int m0 = ss & (same_s[d0 + 0] ^ 1);
        const int m1 = ss & (same_s[d0 + 1] ^ 1);
        const int m2 = ss & (same_s[d0 + 2] ^ 1);
        const int m3 = ss & (same_s[d0 + 3] ^ 1);
        pv.x = m0 ? ps : 0.0f;  nv.x = m0 ? nsim_s[d0 + 0] : 0.0f;  mv.x = (float)m0;
        pv.y = m1 ? ps : 0.0f;  nv.y = m1 ? nsim_s[d0 + 1] : 0.0f;  mv.y = (float)m1;
        pv.z = m2 ? ps : 0.0f;  nv.z = m2 ? nsim_s[d0 + 2] : 0.0f;  mv.z = (float)m2;
        pv.w = m3 ? ps : 0.0f;  nv.w = m3 ? nsim_s[d0 + 3] : 0.0f;  mv.w = (float)m3;
    }
    pos4[tid]  = pv;
    neg4[tid]  = nv;
    mask4[tid] = mv;
}

extern "C" void kernel_launch(void* const* d_in, const int* in_sizes, int n_in,
                              void* d_out, int out_size, void* d_ws, size_t ws_size,
                              hipStream_t stream) {
    const float* semb    = (const float*)d_in[0];
    const int*   slabels = (const int*)d_in[1];
    const int*   topk    = (const int*)d_in[2];

    float* out = (float*)d_out;
    const size_t KBTT = (size_t)K * B * T * T;   // 16,777,216
    float* pos   = out;
    float* neg   = out + KBTT;
    float* maskf = out + 2 * KBTT;
    float* nbr   = out + 3 * KBTT;

    distance_layer_kernel<<<dim3(K * B), dim3(256), 0, stream>>>(
        semb, slabels, topk, pos, neg, maskf, nbr);
}